// Round 2
// baseline (2142.508 us; speedup 1.0000x reference)
//
#include <hip/hip_runtime.h>

// Problem: N=2048, F=64, S=512, D=512
//   gi[n,f,g] = sum_s x[n,f,s] * W_ih[f,g,s]   (+ b_ih)
//   r = sig(gi_r + b_hr); z = sig(gi_z + b_hz); n = tanh(gi_n + r*b_hn)
//   h = (1-z)*n                      out shape (N,F,D) fp32
//
// One block: one f, 128 x-rows x 64 d-cols, all 3 gates fused.
// bf16 MFMA 16x16x32, fp32 accum. Reg-staged LDS with XOR swizzle (T2).
// R2: 4 blocks/CU (launch_bounds 256,4) + XCD-aware grid swizzle (T1):
//     each XCD owns 8 consecutive f, d-tile innermost within -> x-tile
//     sharers co-located on one L2.

#define NN 2048
#define FF 64
#define SS 512
#define DD 512

#define BM 128
#define BD 64
#define BK 64
#define NKT (SS / BK)  // 8

typedef float f32x4 __attribute__((ext_vector_type(4)));
typedef __bf16 bf16x8 __attribute__((ext_vector_type(8)));
typedef unsigned short ushort8 __attribute__((ext_vector_type(8)));
typedef unsigned int uint32x4 __attribute__((ext_vector_type(4)));

__device__ __forceinline__ ushort8 cvt8(const f32x4 a, const f32x4 b) {
    ushort8 r;
    r[0] = __builtin_bit_cast(unsigned short, (__bf16)a[0]);
    r[1] = __builtin_bit_cast(unsigned short, (__bf16)a[1]);
    r[2] = __builtin_bit_cast(unsigned short, (__bf16)a[2]);
    r[3] = __builtin_bit_cast(unsigned short, (__bf16)a[3]);
    r[4] = __builtin_bit_cast(unsigned short, (__bf16)b[0]);
    r[5] = __builtin_bit_cast(unsigned short, (__bf16)b[1]);
    r[6] = __builtin_bit_cast(unsigned short, (__bf16)b[2]);
    r[7] = __builtin_bit_cast(unsigned short, (__bf16)b[3]);
    return r;
}

extern "C" __global__ __launch_bounds__(256, 4)
void gru_fused(const float* __restrict__ x, const float* __restrict__ W,
               const float* __restrict__ b_ih, const float* __restrict__ b_hh,
               float* __restrict__ out)
{
    // LDS: A tile [128][64] bf16 (16 KB) at 0; B tile [3][64][64] bf16 (24 KB) at 16384
    __shared__ __align__(16) unsigned char lds[40960];

    const int t     = threadIdx.x;
    const int lane  = t & 63;
    const int wid   = t >> 6;      // 0..3
    const int wm    = wid >> 1;    // M half (0/1)
    const int wd    = wid & 1;     // D half (0/1)
    const int lrow  = lane & 15;
    const int khalf = lane >> 4;   // 0..3

    // ---- XCD-aware work mapping (T1) ----
    // HW round-robins blockIdx.x across 8 XCDs. Give each XCD a contiguous
    // work chunk: 8 consecutive f values, d-tile innermost within each f.
    const int bid  = blockIdx.x;          // 0..8191
    const int xcd  = bid & 7;
    const int lid  = bid >> 3;            // 0..1023
    const int work = xcd * 1024 + lid;
    const int f    = work >> 7;           // 0..63
    const int rem  = work & 127;
    const int n0   = (rem >> 3) * BM;     // 16 m-tiles
    const int d0   = (rem & 7) * BD;      // 8 d-tiles (innermost: share x-tile)

    // ---- staging coords: each thread owns 8-float segments ----
    const int colSeg = t & 7;      // *8 floats within the 64-wide K slab
    const int rBase  = t >> 3;     // 0..31

    const float* aPtr[4];
    int aOff[4];
#pragma unroll
    for (int p = 0; p < 4; ++p) {
        int row = rBase + 32 * p;                       // 0..127
        aPtr[p] = x + ((long)(n0 + row) * FF + f) * SS + colSeg * 8;
        aOff[p] = row * 128 + ((colSeg * 16) ^ ((row & 7) << 4));
    }
    const float* bPtr[6];
    int bOff[6];
#pragma unroll
    for (int p = 0; p < 6; ++p) {
        int ra   = rBase + 32 * p;                      // 0..191
        int gate = ra >> 6;                             // 0..2
        int dr   = ra & 63;
        bPtr[p] = W + ((long)f * (3 * DD) + gate * DD + d0 + dr) * SS + colSeg * 8;
        bOff[p] = 16384 + gate * 8192 + dr * 128 + ((colSeg * 16) ^ ((dr & 7) << 4));
    }

    f32x4 acc[3][4][2];
#pragma unroll
    for (int g = 0; g < 3; ++g)
#pragma unroll
        for (int i = 0; i < 4; ++i)
#pragma unroll
            for (int j = 0; j < 2; ++j)
                acc[g][i][j] = (f32x4){0.f, 0.f, 0.f, 0.f};

    // ---- prologue: load K-tile 0 into regs ----
    f32x4 va[4][2], vb[6][2];
#pragma unroll
    for (int p = 0; p < 4; ++p) {
        const f32x4* g = (const f32x4*)aPtr[p];
        va[p][0] = g[0]; va[p][1] = g[1];
    }
#pragma unroll
    for (int p = 0; p < 6; ++p) {
        const f32x4* g = (const f32x4*)bPtr[p];
        vb[p][0] = g[0]; vb[p][1] = g[1];
    }

    for (int kt = 0; kt < NKT; ++kt) {
        __syncthreads();  // previous iteration's ds_reads complete
#pragma unroll
        for (int p = 0; p < 4; ++p)
            *(ushort8*)(lds + aOff[p]) = cvt8(va[p][0], va[p][1]);
#pragma unroll
        for (int p = 0; p < 6; ++p)
            *(ushort8*)(lds + bOff[p]) = cvt8(vb[p][0], vb[p][1]);
        __syncthreads();

        // issue next tile's global loads early (hide HBM under MFMA)
        if (kt + 1 < NKT) {
            const long koff = (long)(kt + 1) * BK;
#pragma unroll
            for (int p = 0; p < 4; ++p) {
                const f32x4* g = (const f32x4*)(aPtr[p] + koff);
                va[p][0] = g[0]; va[p][1] = g[1];
            }
#pragma unroll
            for (int p = 0; p < 6; ++p) {
                const f32x4* g = (const f32x4*)(bPtr[p] + koff);
                vb[p][0] = g[0]; vb[p][1] = g[1];
            }
        }

#pragma unroll
        for (int kb = 0; kb < 2; ++kb) {
            bf16x8 af[4];
#pragma unroll
            for (int i = 0; i < 4; ++i) {
                int row = wm * 64 + i * 16 + lrow;
                int off = row * 128 + ((kb * 64 + khalf * 16) ^ ((row & 7) << 4));
                af[i] = __builtin_bit_cast(bf16x8, *(const uint32x4*)(lds + off));
            }
            bf16x8 bfr[3][2];
#pragma unroll
            for (int g = 0; g < 3; ++g)
#pragma unroll
                for (int j = 0; j < 2; ++j) {
                    int dr  = wd * 32 + j * 16 + lrow;
                    int off = 16384 + g * 8192 + dr * 128 +
                              ((kb * 64 + khalf * 16) ^ ((dr & 7) << 4));
                    bfr[g][j] = __builtin_bit_cast(bf16x8, *(const uint32x4*)(lds + off));
                }
#pragma unroll
            for (int g = 0; g < 3; ++g)
#pragma unroll
                for (int i = 0; i < 4; ++i)
#pragma unroll
                    for (int j = 0; j < 2; ++j)
                        acc[g][i][j] = __builtin_amdgcn_mfma_f32_16x16x32_bf16(
                            af[i], bfr[g][j], acc[g][i][j], 0, 0, 0);
        }
    }

    // ---- fused gate epilogue ----
    const long bBase = (long)f * (3 * DD);
#pragma unroll
    for (int j = 0; j < 2; ++j) {
        int d = d0 + wd * 32 + j * 16 + lrow;
        float bihr = b_ih[bBase + d];
        float bihz = b_ih[bBase + DD + d];
        float bihn = b_ih[bBase + 2 * DD + d];
        float bhr  = b_hh[bBase + d];
        float bhz  = b_hh[bBase + DD + d];
        float bhn  = b_hh[bBase + 2 * DD + d];
#pragma unroll
        for (int i = 0; i < 4; ++i) {
#pragma unroll
            for (int q = 0; q < 4; ++q) {
                int row = wm * 64 + i * 16 + khalf * 4 + q;
                float gr = acc[0][i][j][q] + bihr + bhr;
                float gz = acc[1][i][j][q] + bihz + bhz;
                float gy = acc[2][i][j][q] + bihn;
                float r  = 1.0f / (1.0f + __expf(-gr));
                float z  = 1.0f / (1.0f + __expf(-gz));
                float nv = tanhf(gy + r * bhn);
                long oi  = ((long)(n0 + row) * FF + f) * DD + d;
                out[oi]  = (1.0f - z) * nv;
            }
        }
    }
}

extern "C" void kernel_launch(void* const* d_in, const int* in_sizes, int n_in,
                              void* d_out, int out_size, void* d_ws, size_t ws_size,
                              hipStream_t stream) {
    const float* x   = (const float*)d_in[0];
    const float* W   = (const float*)d_in[1];
    const float* bih = (const float*)d_in[2];
    const float* bhh = (const float*)d_in[3];
    float* out       = (float*)d_out;

    dim3 grid(8192);      // flat; XCD-aware remap inside kernel
    dim3 block(256);
    gru_fused<<<grid, block, 0, stream>>>(x, W, bih, bhh, out);
}

// Round 3
// 481.159 us; speedup vs baseline: 4.4528x; 4.4528x over previous
//
#include <hip/hip_runtime.h>

// Problem: N=2048, F=64, S=512, D=512
//   gi[n,f,g] = sum_s x[n,f,s] * W_ih[f,g,s]   (+ b_ih)
//   r = sig(gi_r + b_hr); z = sig(gi_z + b_hz); n = tanh(gi_n + r*b_hn)
//   h = (1-z)*n                      out shape (N,F,D) fp32
//
// One block: one f, 128 x-rows x 32 d-cols, all 3 gates fused.
// bf16 MFMA 16x16x32, fp32 accum. Reg-staged LDS with XOR swizzle (T2).
// R3: BD 64->32 to shed regs (acc 96->48, staging 80->56) so 3 blocks/CU
//     fits WITHOUT spilling (R2's launch_bounds(256,4) spilled 6 GB).
//     launch_bounds(256,3); T1 XCD mapping kept; tanh via __expf.

#define NN 2048
#define FF 64
#define SS 512
#define DD 512

#define BM 128
#define BD 32
#define BK 64
#define NKT (SS / BK)  // 8

typedef float f32x4 __attribute__((ext_vector_type(4)));
typedef __bf16 bf16x8 __attribute__((ext_vector_type(8)));
typedef unsigned short ushort8 __attribute__((ext_vector_type(8)));
typedef unsigned int uint32x4 __attribute__((ext_vector_type(4)));

__device__ __forceinline__ ushort8 cvt8(const f32x4 a, const f32x4 b) {
    ushort8 r;
    r[0] = __builtin_bit_cast(unsigned short, (__bf16)a[0]);
    r[1] = __builtin_bit_cast(unsigned short, (__bf16)a[1]);
    r[2] = __builtin_bit_cast(unsigned short, (__bf16)a[2]);
    r[3] = __builtin_bit_cast(unsigned short, (__bf16)a[3]);
    r[4] = __builtin_bit_cast(unsigned short, (__bf16)b[0]);
    r[5] = __builtin_bit_cast(unsigned short, (__bf16)b[1]);
    r[6] = __builtin_bit_cast(unsigned short, (__bf16)b[2]);
    r[7] = __builtin_bit_cast(unsigned short, (__bf16)b[3]);
    return r;
}

__device__ __forceinline__ float fast_sigmoid(float v) {
    return 1.0f / (1.0f + __expf(-v));
}
__device__ __forceinline__ float fast_tanh(float v) {
    // tanh(x) = 1 - 2/(exp(2x)+1)
    return 1.0f - 2.0f / (__expf(2.0f * v) + 1.0f);
}

extern "C" __global__ __launch_bounds__(256, 3)
void gru_fused(const float* __restrict__ x, const float* __restrict__ W,
               const float* __restrict__ b_ih, const float* __restrict__ b_hh,
               float* __restrict__ out)
{
    // LDS: A tile [128][64] bf16 (16 KB) at 0; B tile [3][32][64] bf16 (12 KB) at 16384
    __shared__ __align__(16) unsigned char lds[28672];

    const int t     = threadIdx.x;
    const int lane  = t & 63;
    const int wid   = t >> 6;      // 0..3
    const int wm    = wid >> 1;    // M half (0/1)
    const int wd    = wid & 1;     // D half (0/1)
    const int lrow  = lane & 15;
    const int khalf = lane >> 4;   // 0..3

    // ---- XCD-aware work mapping (T1): each XCD owns 8 consecutive f,
    //      16 d-tiles innermost (share one x-tile in L2).
    const int bid  = blockIdx.x;          // 0..16383
    const int xcd  = bid & 7;
    const int lid  = bid >> 3;            // 0..2047
    const int work = xcd * 2048 + lid;
    const int f    = work >> 8;           // 0..63
    const int rem  = work & 255;
    const int n0   = (rem >> 4) * BM;     // 16 m-tiles
    const int d0   = (rem & 15) * BD;     // 16 d-tiles (innermost)

    // ---- staging coords: each thread owns 8-float segments ----
    const int colSeg = t & 7;      // *8 floats within the 64-wide K slab
    const int rBase  = t >> 3;     // 0..31

    const float* aPtr[4];
    int aOff[4];
#pragma unroll
    for (int p = 0; p < 4; ++p) {
        int row = rBase + 32 * p;                       // 0..127
        aPtr[p] = x + ((long)(n0 + row) * FF + f) * SS + colSeg * 8;
        aOff[p] = row * 128 + ((colSeg * 16) ^ ((row & 7) << 4));
    }
    const float* bPtr[3];
    int bOff[3];
#pragma unroll
    for (int p = 0; p < 3; ++p) {
        int ra   = rBase + 32 * p;                      // 0..95
        int gate = ra >> 5;                             // 0..2
        int dr   = ra & 31;
        bPtr[p] = W + ((long)f * (3 * DD) + gate * DD + d0 + dr) * SS + colSeg * 8;
        bOff[p] = 16384 + gate * 4096 + dr * 128 + ((colSeg * 16) ^ ((dr & 7) << 4));
    }

    f32x4 acc[3][4];
#pragma unroll
    for (int g = 0; g < 3; ++g)
#pragma unroll
        for (int i = 0; i < 4; ++i)
            acc[g][i] = (f32x4){0.f, 0.f, 0.f, 0.f};

    // ---- prologue: load K-tile 0 into regs ----
    f32x4 va[4][2], vb[3][2];
#pragma unroll
    for (int p = 0; p < 4; ++p) {
        const f32x4* g = (const f32x4*)aPtr[p];
        va[p][0] = g[0]; va[p][1] = g[1];
    }
#pragma unroll
    for (int p = 0; p < 3; ++p) {
        const f32x4* g = (const f32x4*)bPtr[p];
        vb[p][0] = g[0]; vb[p][1] = g[1];
    }

    for (int kt = 0; kt < NKT; ++kt) {
        __syncthreads();  // previous iteration's ds_reads complete
#pragma unroll
        for (int p = 0; p < 4; ++p)
            *(ushort8*)(lds + aOff[p]) = cvt8(va[p][0], va[p][1]);
#pragma unroll
        for (int p = 0; p < 3; ++p)
            *(ushort8*)(lds + bOff[p]) = cvt8(vb[p][0], vb[p][1]);
        __syncthreads();

        // issue next tile's global loads early (hide HBM under MFMA)
        if (kt + 1 < NKT) {
            const long koff = (long)(kt + 1) * BK;
#pragma unroll
            for (int p = 0; p < 4; ++p) {
                const f32x4* g = (const f32x4*)(aPtr[p] + koff);
                va[p][0] = g[0]; va[p][1] = g[1];
            }
#pragma unroll
            for (int p = 0; p < 3; ++p) {
                const f32x4* g = (const f32x4*)(bPtr[p] + koff);
                vb[p][0] = g[0]; vb[p][1] = g[1];
            }
        }

#pragma unroll
        for (int kb = 0; kb < 2; ++kb) {
            bf16x8 af[4];
#pragma unroll
            for (int i = 0; i < 4; ++i) {
                int row = wm * 64 + i * 16 + lrow;
                int off = row * 128 + ((kb * 64 + khalf * 16) ^ ((row & 7) << 4));
                af[i] = __builtin_bit_cast(bf16x8, *(const uint32x4*)(lds + off));
            }
            bf16x8 bfr[3];
#pragma unroll
            for (int g = 0; g < 3; ++g) {
                int dr  = wd * 16 + lrow;
                int off = 16384 + g * 4096 + dr * 128 +
                          ((kb * 64 + khalf * 16) ^ ((dr & 7) << 4));
                bfr[g] = __builtin_bit_cast(bf16x8, *(const uint32x4*)(lds + off));
            }
#pragma unroll
            for (int g = 0; g < 3; ++g)
#pragma unroll
                for (int i = 0; i < 4; ++i)
                    acc[g][i] = __builtin_amdgcn_mfma_f32_16x16x32_bf16(
                        af[i], bfr[g], acc[g][i], 0, 0, 0);
        }
    }

    // ---- fused gate epilogue ----
    const long bBase = (long)f * (3 * DD);
    {
        int d = d0 + wd * 16 + lrow;
        float bihr = b_ih[bBase + d];
        float bihz = b_ih[bBase + DD + d];
        float bihn = b_ih[bBase + 2 * DD + d];
        float bhr  = b_hh[bBase + d];
        float bhz  = b_hh[bBase + DD + d];
        float bhn  = b_hh[bBase + 2 * DD + d];
#pragma unroll
        for (int i = 0; i < 4; ++i) {
#pragma unroll
            for (int q = 0; q < 4; ++q) {
                int row = wm * 64 + i * 16 + khalf * 4 + q;
                float gr = acc[0][i][q] + bihr + bhr;
                float gz = acc[1][i][q] + bihz + bhz;
                float gy = acc[2][i][q] + bihn;
                float r  = fast_sigmoid(gr);
                float z  = fast_sigmoid(gz);
                float nv = fast_tanh(gy + r * bhn);
                long oi  = ((long)(n0 + row) * FF + f) * DD + d;
                out[oi]  = (1.0f - z) * nv;
            }
        }
    }
}

extern "C" void kernel_launch(void* const* d_in, const int* in_sizes, int n_in,
                              void* d_out, int out_size, void* d_ws, size_t ws_size,
                              hipStream_t stream) {
    const float* x   = (const float*)d_in[0];
    const float* W   = (const float*)d_in[1];
    const float* bih = (const float*)d_in[2];
    const float* bhh = (const float*)d_in[3];
    float* out       = (float*)d_out;

    dim3 grid(16384);     // flat; XCD-aware remap inside kernel
    dim3 block(256);
    gru_fused<<<grid, block, 0, stream>>>(x, W, bih, bhh, out);
}

// Round 4
// 441.867 us; speedup vs baseline: 4.8488x; 1.0889x over previous
//
#include <hip/hip_runtime.h>
#include <stdint.h>

// Problem: N=2048, F=64, S=512, D=512
//   gi[n,f,g] = sum_s x[n,f,s] * W_ih[f,g,s]   (+ b_ih)
//   r=sig(gi_r+b_hr); z=sig(gi_z+b_hz); n=tanh(gi_n + r*b_hn); h=(1-z)*n
//
// R4: two prepass kernels convert x,W -> bf16 tiles stored in EXACT LDS-image
//     order (XOR swizzle baked in). Main GEMM stages via global_load_lds
//     (identity 16B copies, zero VALU staging), m97 2-barrier structure.
//     BM=128, BD=64 (x3 gates), BK=64, 4 waves, launch_bounds(256,3).

#define NN 2048
#define FF 64
#define SS 512
#define DD 512
#define BM 128
#define BD 64
#define BK 64
#define NKT 8

#define A_SLAB 16384   // 128 rows x 64 k x 2B
#define B_SLAB 24576   // 3 gates x 64 rows x 64 k x 2B
#define XT_BYTES ((long)64 * 16 * 8 * A_SLAB)   // 134217728
#define WT_BYTES ((long)64 * 8 * 8 * B_SLAB)    // 100663296

typedef float f32x4 __attribute__((ext_vector_type(4)));
typedef __bf16 bf16x8 __attribute__((ext_vector_type(8)));
typedef unsigned short ushort8 __attribute__((ext_vector_type(8)));
typedef unsigned int uint32x4 __attribute__((ext_vector_type(4)));

#define AS1 __attribute__((address_space(1)))
#define AS3 __attribute__((address_space(3)))

__device__ __forceinline__ void gload16(const void* gsrc, void* ldst) {
    __builtin_amdgcn_global_load_lds(
        (const AS1 unsigned int*)(uintptr_t)gsrc,
        (AS3 unsigned int*)(unsigned int)(uintptr_t)ldst,
        16, 0, 0);
}

__device__ __forceinline__ ushort8 cvt8(const f32x4 a, const f32x4 b) {
    ushort8 r;
    r[0] = __builtin_bit_cast(unsigned short, (__bf16)a[0]);
    r[1] = __builtin_bit_cast(unsigned short, (__bf16)a[1]);
    r[2] = __builtin_bit_cast(unsigned short, (__bf16)a[2]);
    r[3] = __builtin_bit_cast(unsigned short, (__bf16)a[3]);
    r[4] = __builtin_bit_cast(unsigned short, (__bf16)b[0]);
    r[5] = __builtin_bit_cast(unsigned short, (__bf16)b[1]);
    r[6] = __builtin_bit_cast(unsigned short, (__bf16)b[2]);
    r[7] = __builtin_bit_cast(unsigned short, (__bf16)b[3]);
    return r;
}

__device__ __forceinline__ float fast_sigmoid(float v) {
    return 1.0f / (1.0f + __expf(-v));
}
__device__ __forceinline__ float fast_tanh(float v) {
    return 1.0f - 2.0f / (__expf(2.0f * v) + 1.0f);
}

// ---------------- prepass: x -> bf16 LDS-image tiles ----------------
// slab id = (f*16+mt)*8+kt == blockIdx.x. Within slab, 16B seg q (0..1023):
// row r=q>>3, inner=q&7 holds source k-seg s = inner ^ (r&7)  (XOR swizzle).
extern "C" __global__ __launch_bounds__(256)
void prep_x(const float* __restrict__ x, ushort8* __restrict__ xT) {
    const int b  = blockIdx.x;            // 8192
    const int f  = b >> 7;
    const int mt = (b >> 3) & 15;
    const int kt = b & 7;
    const int t  = threadIdx.x;
    const long slab = (long)b * 1024;     // in ushort8 units
#pragma unroll
    for (int p = 0; p < 4; ++p) {
        int q = p * 256 + t;
        int r = q >> 3;
        int s = (q & 7) ^ (r & 7);
        const f32x4* src = (const f32x4*)(x + ((long)(mt * BM + r) * FF + f) * SS
                                          + kt * BK + s * 8);
        xT[slab + q] = cvt8(src[0], src[1]);
    }
}

// slab id = (f*8+dt)*8+kt == blockIdx.x. Seg q (0..1535): gate g=q>>9,
// row rr=(q>>3)&63, inner=q&7 holds k-seg s = inner ^ (rr&7).
extern "C" __global__ __launch_bounds__(256)
void prep_w(const float* __restrict__ W, ushort8* __restrict__ wT) {
    const int b  = blockIdx.x;            // 4096
    const int f  = b >> 6;
    const int dt = (b >> 3) & 7;
    const int kt = b & 7;
    const int t  = threadIdx.x;
    const long slab = (long)b * 1536;
#pragma unroll
    for (int p = 0; p < 6; ++p) {
        int q  = p * 256 + t;
        int g  = q >> 9;
        int rr = (q >> 3) & 63;
        int s  = (q & 7) ^ (rr & 7);
        const f32x4* src = (const f32x4*)(W + ((long)f * 1536 + g * DD + dt * BD + rr) * SS
                                          + kt * BK + s * 8);
        wT[slab + q] = cvt8(src[0], src[1]);
    }
}

// ---------------- main GEMM + fused gates (m97 structure) ----------------
extern "C" __global__ __launch_bounds__(256, 3)
void gru_gemm(const unsigned char* __restrict__ xT, const unsigned char* __restrict__ wT,
              const float* __restrict__ b_ih, const float* __restrict__ b_hh,
              float* __restrict__ out)
{
    // LDS: A [128][64]bf16 swizzled (16KB) @0; B [3][64][64]bf16 (24KB) @16384
    __shared__ __align__(16) unsigned char lds[40960];

    const int t     = threadIdx.x;
    const int lane  = t & 63;
    const int wid   = t >> 6;
    const int wm    = wid >> 1;
    const int wd    = wid & 1;
    const int lrow  = lane & 15;
    const int khalf = lane >> 4;

    // T1 XCD mapping: each XCD owns 8 consecutive f; d-tile innermost
    const int bid  = blockIdx.x;          // 0..8191
    const int xcd  = bid & 7;
    const int lid  = bid >> 3;
    const int work = xcd * 1024 + lid;
    const int f    = work >> 7;           // 0..63
    const int rem  = work & 127;
    const int mt   = rem >> 3;            // 0..15
    const int dt   = rem & 7;             // 0..7
    const int n0   = mt * BM;
    const int d0   = dt * BD;

    const unsigned char* aSlab = xT + (long)((f * 16 + mt) * 8) * A_SLAB;
    const unsigned char* bSlab = wT + (long)((f * 8 + dt) * 8) * B_SLAB;
    const int ldsW = (t & 192) * 16;      // wid*1024 (wave-uniform)

    f32x4 acc[3][4][2];
#pragma unroll
    for (int g = 0; g < 3; ++g)
#pragma unroll
        for (int i = 0; i < 4; ++i)
#pragma unroll
            for (int j = 0; j < 2; ++j)
                acc[g][i][j] = (f32x4){0.f, 0.f, 0.f, 0.f};

    for (int kt = 0; kt < NKT; ++kt) {
        __syncthreads();   // prev iteration's ds_reads done
        // stage K-tile kt: identity 16B copies (images are pre-swizzled)
#pragma unroll
        for (int p = 0; p < 4; ++p)
            gload16(aSlab + kt * A_SLAB + (p * 256 + t) * 16,
                    lds + p * 4096 + ldsW);
#pragma unroll
        for (int p = 0; p < 6; ++p)
            gload16(bSlab + kt * B_SLAB + (p * 256 + t) * 16,
                    lds + 16384 + p * 4096 + ldsW);
        __syncthreads();   // drains vmcnt -> tile visible

#pragma unroll
        for (int kb = 0; kb < 2; ++kb) {
            bf16x8 af[4];
#pragma unroll
            for (int i = 0; i < 4; ++i) {
                int row = wm * 64 + i * 16 + lrow;
                int off = row * 128 + ((kb * 64 + khalf * 16) ^ ((row & 7) << 4));
                af[i] = __builtin_bit_cast(bf16x8, *(const uint32x4*)(lds + off));
            }
            bf16x8 bfr[3][2];
#pragma unroll
            for (int g = 0; g < 3; ++g)
#pragma unroll
                for (int j = 0; j < 2; ++j) {
                    int dr  = wd * 32 + j * 16 + lrow;
                    int off = 16384 + g * 8192 + dr * 128 +
                              ((kb * 64 + khalf * 16) ^ ((dr & 7) << 4));
                    bfr[g][j] = __builtin_bit_cast(bf16x8, *(const uint32x4*)(lds + off));
                }
#pragma unroll
            for (int g = 0; g < 3; ++g)
#pragma unroll
                for (int i = 0; i < 4; ++i)
#pragma unroll
                    for (int j = 0; j < 2; ++j)
                        acc[g][i][j] = __builtin_amdgcn_mfma_f32_16x16x32_bf16(
                            af[i], bfr[g][j], acc[g][i][j], 0, 0, 0);
        }
    }

    // fused gate epilogue
    const long bBase = (long)f * (3 * DD);
#pragma unroll
    for (int j = 0; j < 2; ++j) {
        int d = d0 + wd * 32 + j * 16 + lrow;
        float bihr = b_ih[bBase + d];
        float bihz = b_ih[bBase + DD + d];
        float bihn = b_ih[bBase + 2 * DD + d];
        float bhr  = b_hh[bBase + d];
        float bhz  = b_hh[bBase + DD + d];
        float bhn  = b_hh[bBase + 2 * DD + d];
#pragma unroll
        for (int i = 0; i < 4; ++i) {
#pragma unroll
            for (int q = 0; q < 4; ++q) {
                int row = wm * 64 + i * 16 + khalf * 4 + q;
                float gr = acc[0][i][j][q] + bihr + bhr;
                float gz = acc[1][i][j][q] + bihz + bhz;
                float gy = acc[2][i][j][q] + bihn;
                float r  = fast_sigmoid(gr);
                float z  = fast_sigmoid(gz);
                float nv = fast_tanh(gy + r * bhn);
                long oi  = ((long)(n0 + row) * FF + f) * DD + d;
                out[oi]  = (1.0f - z) * nv;
            }
        }
    }
}

// ---------------- fallback (R3 kernel) if ws too small ----------------
extern "C" __global__ __launch_bounds__(256, 3)
void gru_fused_fb(const float* __restrict__ x, const float* __restrict__ W,
                  const float* __restrict__ b_ih, const float* __restrict__ b_hh,
                  float* __restrict__ out)
{
    __shared__ __align__(16) unsigned char lds[28672];
    const int t     = threadIdx.x;
    const int lane  = t & 63;
    const int wid   = t >> 6;
    const int wm    = wid >> 1;
    const int wd    = wid & 1;
    const int lrow  = lane & 15;
    const int khalf = lane >> 4;
    const int bid  = blockIdx.x;
    const int xcd  = bid & 7;
    const int lid  = bid >> 3;
    const int work = xcd * 2048 + lid;
    const int f    = work >> 8;
    const int rem  = work & 255;
    const int n0   = (rem >> 4) * BM;
    const int d0   = (rem & 15) * 32;
    const int colSeg = t & 7;
    const int rBase  = t >> 3;
    const float* aPtr[4]; int aOff[4];
#pragma unroll
    for (int p = 0; p < 4; ++p) {
        int row = rBase + 32 * p;
        aPtr[p] = x + ((long)(n0 + row) * FF + f) * SS + colSeg * 8;
        aOff[p] = row * 128 + ((colSeg * 16) ^ ((row & 7) << 4));
    }
    const float* bPtr[3]; int bOff[3];
#pragma unroll
    for (int p = 0; p < 3; ++p) {
        int ra = rBase + 32 * p;
        int gate = ra >> 5, dr = ra & 31;
        bPtr[p] = W + ((long)f * 1536 + gate * DD + d0 + dr) * SS + colSeg * 8;
        bOff[p] = 16384 + gate * 4096 + dr * 128 + ((colSeg * 16) ^ ((dr & 7) << 4));
    }
    f32x4 acc[3][4];
#pragma unroll
    for (int g = 0; g < 3; ++g)
#pragma unroll
        for (int i = 0; i < 4; ++i) acc[g][i] = (f32x4){0.f, 0.f, 0.f, 0.f};
    f32x4 va[4][2], vb[3][2];
#pragma unroll
    for (int p = 0; p < 4; ++p) { const f32x4* g = (const f32x4*)aPtr[p]; va[p][0] = g[0]; va[p][1] = g[1]; }
#pragma unroll
    for (int p = 0; p < 3; ++p) { const f32x4* g = (const f32x4*)bPtr[p]; vb[p][0] = g[0]; vb[p][1] = g[1]; }
    for (int kt = 0; kt < NKT; ++kt) {
        __syncthreads();
#pragma unroll
        for (int p = 0; p < 4; ++p) *(ushort8*)(lds + aOff[p]) = cvt8(va[p][0], va[p][1]);
#pragma unroll
        for (int p = 0; p < 3; ++p) *(ushort8*)(lds + bOff[p]) = cvt8(vb[p][0], vb[p][1]);
        __syncthreads();
        if (kt + 1 < NKT) {
            const long koff = (long)(kt + 1) * BK;
#pragma unroll
            for (int p = 0; p < 4; ++p) { const f32x4* g = (const f32x4*)(aPtr[p] + koff); va[p][0] = g[0]; va[p][1] = g[1]; }
#pragma unroll
            for (int p = 0; p < 3; ++p) { const f32x4* g = (const f32x4*)(bPtr[p] + koff); vb[p][0] = g[0]; vb[p][1] = g[1]; }
        }
#pragma unroll
        for (int kb = 0; kb < 2; ++kb) {
            bf16x8 af[4];
#pragma unroll
            for (int i = 0; i < 4; ++i) {
                int row = wm * 64 + i * 16 + lrow;
                int off = row * 128 + ((kb * 64 + khalf * 16) ^ ((row & 7) << 4));
                af[i] = __builtin_bit_cast(bf16x8, *(const uint32x4*)(lds + off));
            }
            bf16x8 bfr[3];
#pragma unroll
            for (int g = 0; g < 3; ++g) {
                int dr = wd * 16 + lrow;
                int off = 16384 + g * 4096 + dr * 128 + ((kb * 64 + khalf * 16) ^ ((dr & 7) << 4));
                bfr[g] = __builtin_bit_cast(bf16x8, *(const uint32x4*)(lds + off));
            }
#pragma unroll
            for (int g = 0; g < 3; ++g)
#pragma unroll
                for (int i = 0; i < 4; ++i)
                    acc[g][i] = __builtin_amdgcn_mfma_f32_16x16x32_bf16(af[i], bfr[g], acc[g][i], 0, 0, 0);
        }
    }
    const long bBase = (long)f * 1536;
    {
        int d = d0 + wd * 16 + lrow;
        float bihr = b_ih[bBase + d], bihz = b_ih[bBase + DD + d], bihn = b_ih[bBase + 2 * DD + d];
        float bhr = b_hh[bBase + d], bhz = b_hh[bBase + DD + d], bhn = b_hh[bBase + 2 * DD + d];
#pragma unroll
        for (int i = 0; i < 4; ++i)
#pragma unroll
            for (int q = 0; q < 4; ++q) {
                int row = wm * 64 + i * 16 + khalf * 4 + q;
                float r  = fast_sigmoid(acc[0][i][q] + bihr + bhr);
                float z  = fast_sigmoid(acc[1][i][q] + bihz + bhz);
                float nv = fast_tanh(acc[2][i][q] + bihn + r * bhn);
                out[((long)(n0 + row) * FF + f) * DD + d] = (1.0f - z) * nv;
            }
    }
}

extern "C" void kernel_launch(void* const* d_in, const int* in_sizes, int n_in,
                              void* d_out, int out_size, void* d_ws, size_t ws_size,
                              hipStream_t stream) {
    const float* x   = (const float*)d_in[0];
    const float* W   = (const float*)d_in[1];
    const float* bih = (const float*)d_in[2];
    const float* bhh = (const float*)d_in[3];
    float* out       = (float*)d_out;

    if (ws_size >= (size_t)(XT_BYTES + WT_BYTES)) {
        unsigned char* xT = (unsigned char*)d_ws;
        unsigned char* wT = xT + XT_BYTES;
        prep_x<<<dim3(8192), dim3(256), 0, stream>>>(x, (ushort8*)xT);
        prep_w<<<dim3(4096), dim3(256), 0, stream>>>(W, (ushort8*)wT);
        gru_gemm<<<dim3(8192), dim3(256), 0, stream>>>(xT, wT, bih, bhh, out);
    } else {
        gru_fused_fb<<<dim3(16384), dim3(256), 0, stream>>>(x, W, bih, bhh, out);
    }
}